// Round 7
// baseline (523.247 us; speedup 1.0000x reference)
//
#include <hip/hip_runtime.h>
#include <hip/hip_bf16.h>

#define N_    32
#define T_    1600
#define C_    1024
#define S_    200
#define L_    401       // 2*S+1
#define LP_   512       // padded
#define BLANK_ 4
#define LN2_  0.69314718055994531f
#define L2E_  1.44269504088896341f
#define DPF   8

#if __has_builtin(__builtin_amdgcn_exp2f)
#define EXP2(x) __builtin_amdgcn_exp2f(x)
#else
#define EXP2(x) exp2f(x)
#endif
#if __has_builtin(__builtin_amdgcn_rcpf)
#define RCP(x) __builtin_amdgcn_rcpf(x)
#else
#define RCP(x) (1.0f / (x))
#endif

// Kernel 1: one wave per (n,t) row. Wave-shuffle softmax, row staged in LDS,
// gather ext-label classes, write LINEAR probabilities P[n][t][l].
// Junk positions (l > 2*tgt_len[n], never read) are zeroed so their alphas
// stay exactly 0 and never pollute the renorm max in k_ctc.
__global__ __launch_bounds__(256)
void k_softmax_gather(const float* __restrict__ logits,
                      const int* __restrict__ targets,
                      const int* __restrict__ tgt_len,
                      float* __restrict__ P) {
  const int row  = blockIdx.x * 4 + (threadIdx.x >> 6);  // n*T_ + t
  const int lane = threadIdx.x & 63;
  const int wv   = threadIdx.x >> 6;
  const int n    = row / T_;
  const float* x = logits + (size_t)row * C_;
  __shared__ float sh[4][C_];

  float4 v[4];
#pragma unroll
  for (int i = 0; i < 4; ++i)
    v[i] = reinterpret_cast<const float4*>(x)[i * 64 + lane];

  float mx = v[0].x;
#pragma unroll
  for (int i = 0; i < 4; ++i)
    mx = fmaxf(mx, fmaxf(fmaxf(v[i].x, v[i].y), fmaxf(v[i].z, v[i].w)));
#pragma unroll
  for (int i = 1; i < 64; i <<= 1) mx = fmaxf(mx, __shfl_xor(mx, i));

  float s = 0.0f;
#pragma unroll
  for (int i = 0; i < 4; ++i) {
    s += EXP2((v[i].x - mx) * L2E_) + EXP2((v[i].y - mx) * L2E_)
       + EXP2((v[i].z - mx) * L2E_) + EXP2((v[i].w - mx) * L2E_);
  }
#pragma unroll
  for (int i = 1; i < 64; i <<= 1) s += __shfl_xor(s, i);
  float rz = RCP(s);

#pragma unroll
  for (int i = 0; i < 4; ++i)
    reinterpret_cast<float4*>(sh[wv])[i * 64 + lane] = v[i];
  __syncthreads();

  const int* tg = targets + n * S_;
  const int lmax = 2 * tgt_len[n];   // live region: l in [0, 2*tl]
  float* out = P + (size_t)row * LP_;
#pragma unroll
  for (int i = 0; i < 8; ++i) {
    int l = lane + i * 64;
    float p = 0.0f;
    if (l <= lmax) {
      int c = (l & 1) ? tg[(l - 1) >> 1] : BLANK_;
      p = EXP2((sh[wv][c] - mx) * L2E_) * rz;
    }
    out[l] = p;
  }
}

// Kernel 2: CTC forward, ONE wave per sequence, lane owns 8 contiguous
// positions. Only ONE cross-lane value per step (alpha[l-1] for j=0),
// shuffled one step AHEAD so shuffle latency hides under the issue stream.
//
// History: R1 (f64, compiler ping-pong loads) 142us and R4 (f64, asm-forced
// pipeline) 145us are identical at ~218 cyc/step => step math dominates, not
// load scheduling. R5/R6 (f32 + asm pipeline) both SIGABRT'd; all memory
// addressing was identical to passing R4, so the asm-float4 machinery under
// changed register pressure is the only kernel-side suspect (this backend
// already showed asm-aggregate fragility in R3). THIS ROUND: the exact R1
// skeleton (PASSED; no inline asm anywhere) with register-only edits -- f32
// state (2 cyc/op, zero cvt since P is f32), wave-uniform f32 renorm every 4
// steps: butterfly fmax -> R = 125 - bexp (wave max into [2^-2,2^-1)), 8x
// v_ldexp_f32, 'up' rides along, Etot wave-uniform. Numerics: worst 4-step
// decay >= 2^-82 abs (>> 2^-126 f32 min normal); relative flush at 2^-149 is
// finer than the f32-logspace reference can represent (~16 nat window).
__global__ __launch_bounds__(64, 1)
void k_ctc(const float* __restrict__ P,
           const int* __restrict__ targets,
           const int* __restrict__ in_len,
           const int* __restrict__ tgt_len,
           float* __restrict__ nll_out) {
  const int n = blockIdx.x;
  const int lane = threadIdx.x;
  const int Tn = in_len[n];
  const float* g = P + (size_t)n * T_ * LP_;
  const int* tg = targets + n * S_;

  // skip multipliers for odd positions j=1,3,5,7 -> label index m0+0..3
  const int m0 = lane * 4;
  auto skv = [&](int m) -> float {
    int mi = (m >= 1 && m < S_) ? m : 1;     // clamp: no OOB read
    return (m >= 1 && m < S_ && tg[mi] != tg[mi - 1]) ? 1.0f : 0.0f;
  };
  const float sk1 = skv(m0), sk3 = skv(m0 + 1);
  const float sk5 = skv(m0 + 2), sk7 = skv(m0 + 3);

  float a0 = 0.0f, a1 = 0.0f, a2 = 0.0f, a3 = 0.0f;
  float a4 = 0.0f, a5 = 0.0f, a6 = 0.0f, a7 = 0.0f;
  float up = 0.0f;   // alpha(t-1, lane*8 - 1): shuffled during previous step
  if (lane == 0) { a0 = g[0]; a1 = g[1]; }
  int Etot = 0;      // true alpha = a * 2^Etot (wave-uniform)

  const float* gl = g + lane * 8;
  const int src = (lane + 63) & 63;

  auto step = [&](const float4& A, const float4& B) {
    // a7n/a6n first: lane-local only -> shuffle for NEXT step issues early
    float a7n = (a7 + a6 + sk7 * a5) * B.w;
    float a6n = (a6 + a5) * B.z;
    float upn = __shfl(a7n, src);            // consumed next step
    float a5n = (a5 + a4 + sk5 * a3) * B.y;
    float a4n = (a4 + a3) * B.x;
    float a3n = (a3 + a2 + sk3 * a1) * A.w;
    float a2n = (a2 + a1) * A.z;
    float a1n = (a1 + a0 + sk1 * up) * A.y;  // up: already in regs
    float a0n = (a0 + up) * A.x;             // even: no skip ever
    if (lane == 0) upn = 0.0f;               // no predecessor
    a0 = a0n; a1 = a1n; a2 = a2n; a3 = a3n;
    a4 = a4n; a5 = a5n; a6 = a6n; a7 = a7n;
    up = upn;
  };

  // wave-uniform renorm: butterfly fmax gives the identical max on every
  // lane -> identical R -> frame stays wave-uniform (proven R0/R1 topology).
  auto renorm = [&]() {
    float m = fmaxf(fmaxf(fmaxf(a0, a1), fmaxf(a2, a3)),
                    fmaxf(fmaxf(a4, a5), fmaxf(a6, a7)));
#pragma unroll
    for (int i = 1; i < 64; i <<= 1) m = fmaxf(m, __shfl_xor(m, i));
    int R = 125 - ((__float_as_int(m) >> 23) & 0xFF);
    a0 = ldexpf(a0, R); a1 = ldexpf(a1, R); a2 = ldexpf(a2, R);
    a3 = ldexpf(a3, R); a4 = ldexpf(a4, R); a5 = ldexpf(a5, R);
    a6 = ldexpf(a6, R); a7 = ldexpf(a7, R);
    up = ldexpf(up, R);          // pipelined boundary value rides along
    Etot -= R;
  };

  // load rows for one step into a float4 pair (clamped: rows up to T_-1
  // always exist in P; clamped rows are prefetch garbage, never consumed)
  auto ld = [&](int tt, float4& A, float4& B) {
    if (tt > T_ - 1) tt = T_ - 1;
    const float* p = gl + (size_t)tt * LP_;
    A = *reinterpret_cast<const float4*>(p);
    B = *reinterpret_cast<const float4*>(p + 4);
  };

  float4 A0[DPF], B0[DPF], A1[DPF], B1[DPF];
#pragma unroll
  for (int d = 0; d < DPF; ++d) ld(1 + d, A0[d], B0[d]);

  // invariant at each phase top: A0/B0 (resp. A1/B1) hold rows t..t+DPF-1
  int t = 1;
  int rem = Tn - 1;               // total steps to execute (t = 1..Tn-1)
  while (rem >= 2 * DPF) {
    // phase 1: prefetch next block into A1/B1, compute from A0/B0
#pragma unroll
    for (int d = 0; d < DPF; ++d) ld(t + DPF + d, A1[d], B1[d]);
#pragma unroll
    for (int d = 0; d < DPF; ++d) {
      step(A0[d], B0[d]);
      if ((d & 3) == 3) renorm();   // every 4 steps (f32 range budget)
    }
    t += DPF;
    // phase 2: prefetch next block into A0/B0, compute from A1/B1
#pragma unroll
    for (int d = 0; d < DPF; ++d) ld(t + DPF + d, A0[d], B0[d]);
#pragma unroll
    for (int d = 0; d < DPF; ++d) {
      step(A1[d], B1[d]);
      if ((d & 3) == 3) renorm();
    }
    t += DPF;
    rem -= 2 * DPF;
  }
  // rem in [0, 2*DPF-1]; A0/B0 hold rows t..t+DPF-1
  if (rem >= DPF) {
#pragma unroll
    for (int d = 0; d < DPF; ++d) ld(t + DPF + d, A1[d], B1[d]);
#pragma unroll
    for (int d = 0; d < DPF; ++d) {
      step(A0[d], B0[d]);
      if ((d & 3) == 3) renorm();
    }
    t += DPF; rem -= DPF;
#pragma unroll
    for (int d = 0; d < DPF; ++d) {
      if (d < rem) step(A1[d], B1[d]);
      if ((d & 3) == 3) renorm();   // keep cadence through the tail
    }
  } else {
#pragma unroll
    for (int d = 0; d < DPF; ++d) {
      if (d < rem) step(A0[d], B0[d]);
      if ((d & 3) == 3) renorm();
    }
  }

  __shared__ float sa[LP_];
  sa[lane * 8 + 0] = a0; sa[lane * 8 + 1] = a1;
  sa[lane * 8 + 2] = a2; sa[lane * 8 + 3] = a3;
  sa[lane * 8 + 4] = a4; sa[lane * 8 + 5] = a5;
  sa[lane * 8 + 6] = a6; sa[lane * 8 + 7] = a7;
  __syncthreads();
  if (lane == 0) {
    int tl = tgt_len[n];
    double v = (double)sa[2 * tl - 1] + (double)sa[2 * tl];
    int ee;
    double mfr = frexp(v, &ee);
    nll_out[n] = -LN2_ * ((float)(Etot + ee) + log2f((float)mfr));
  }
}

__global__ void k_final(const float* __restrict__ nll,
                        const int* __restrict__ tgt_len,
                        float* __restrict__ out) {
  int lane = threadIdx.x;
  float v = 0.0f;
  if (lane < N_) v = nll[lane] / (float)tgt_len[lane];
#pragma unroll
  for (int i = 1; i < 64; i <<= 1) v += __shfl_xor(v, i);
  if (lane == 0) out[0] = v * (1.0f / N_);
}

__global__ void k_sentinel(float* out) { out[0] = -12345.0f; }

extern "C" void kernel_launch(void* const* d_in, const int* in_sizes, int n_in,
                              void* d_out, int out_size, void* d_ws, size_t ws_size,
                              hipStream_t stream) {
  const float* logits = (const float*)d_in[0];
  const int* targets  = (const int*)d_in[1];
  const int* in_len   = (const int*)d_in[2];
  const int* tgt_len  = (const int*)d_in[3];
  float* out = (float*)d_out;

  size_t gbytes = (size_t)N_ * T_ * LP_ * sizeof(float);  // ~104.9 MB
  if (ws_size < gbytes + 256) {
    k_sentinel<<<1, 1, 0, stream>>>(out);
    return;
  }
  float* G = (float*)d_ws;
  float* nll = (float*)((char*)d_ws + gbytes);

  k_softmax_gather<<<(N_ * T_) / 4, 256, 0, stream>>>(logits, targets, tgt_len, G);
  k_ctc<<<N_, 64, 0, stream>>>(G, targets, in_len, tgt_len, nll);
  k_final<<<1, 64, 0, stream>>>(nll, tgt_len, out);
}

// Round 8
// 506.840 us; speedup vs baseline: 1.0324x; 1.0324x over previous
//
#include <hip/hip_runtime.h>
#include <hip/hip_bf16.h>

#define N_    32
#define T_    1600
#define C_    1024
#define S_    200
#define L_    401       // 2*S+1
#define LP_   512       // padded
#define BLANK_ 4
#define LN2_  0.69314718055994531f
#define L2E_  1.44269504088896341f
#define DPF   8

#if __has_builtin(__builtin_amdgcn_exp2f)
#define EXP2(x) __builtin_amdgcn_exp2f(x)
#else
#define EXP2(x) exp2f(x)
#endif
#if __has_builtin(__builtin_amdgcn_rcpf)
#define RCP(x) __builtin_amdgcn_rcpf(x)
#else
#define RCP(x) (1.0f / (x))
#endif
#if __has_builtin(__builtin_amdgcn_ldexpf)
#define LDX(x, e) __builtin_amdgcn_ldexpf((x), (e))
#else
#define LDX(x, e) ldexpf((x), (e))
#endif

// Kernel 1: one wave per (n,t) row. Wave-shuffle softmax, row staged in LDS,
// gather ext-label classes, write LINEAR probabilities P[n][t][l].
// Junk positions (l > 2*tgt_len[n], never read) are zeroed so their alphas
// stay exactly 0 and never pollute anything downstream.
__global__ __launch_bounds__(256)
void k_softmax_gather(const float* __restrict__ logits,
                      const int* __restrict__ targets,
                      const int* __restrict__ tgt_len,
                      float* __restrict__ P) {
  const int row  = blockIdx.x * 4 + (threadIdx.x >> 6);  // n*T_ + t
  const int lane = threadIdx.x & 63;
  const int wv   = threadIdx.x >> 6;
  const int n    = row / T_;
  const float* x = logits + (size_t)row * C_;
  __shared__ float sh[4][C_];

  float4 v[4];
#pragma unroll
  for (int i = 0; i < 4; ++i)
    v[i] = reinterpret_cast<const float4*>(x)[i * 64 + lane];

  float mx = v[0].x;
#pragma unroll
  for (int i = 0; i < 4; ++i)
    mx = fmaxf(mx, fmaxf(fmaxf(v[i].x, v[i].y), fmaxf(v[i].z, v[i].w)));
#pragma unroll
  for (int i = 1; i < 64; i <<= 1) mx = fmaxf(mx, __shfl_xor(mx, i));

  float s = 0.0f;
#pragma unroll
  for (int i = 0; i < 4; ++i) {
    s += EXP2((v[i].x - mx) * L2E_) + EXP2((v[i].y - mx) * L2E_)
       + EXP2((v[i].z - mx) * L2E_) + EXP2((v[i].w - mx) * L2E_);
  }
#pragma unroll
  for (int i = 1; i < 64; i <<= 1) s += __shfl_xor(s, i);
  float rz = RCP(s);

#pragma unroll
  for (int i = 0; i < 4; ++i)
    reinterpret_cast<float4*>(sh[wv])[i * 64 + lane] = v[i];
  __syncthreads();

  const int* tg = targets + n * S_;
  const int lmax = 2 * tgt_len[n];   // live region: l in [0, 2*tl]
  float* out = P + (size_t)row * LP_;
#pragma unroll
  for (int i = 0; i < 8; ++i) {
    int l = lane + i * 64;
    float p = 0.0f;
    if (l <= lmax) {
      int c = (l & 1) ? tg[(l - 1) >> 1] : BLANK_;
      p = EXP2((sh[wv][c] - mx) * L2E_) * rz;
    }
    out[l] = p;
  }
}

// Kernel 2: CTC forward, ONE wave per sequence, lane owns 8 contiguous
// positions, f32 with PER-LANE exponent frames.
//
// Cycle model (fits R1/R4/R7): f64 step = 112 DP-issue + 20 renorm/32 + ~85
// load stall = 218 cyc (R1/R4); R7's f32 = 48 issue + ~150 BUTTERFLY renorm
// (6 dependent shuffles @ ~100cyc, 1-wave occupancy, every 4 steps) + 85 =
// ~290-350 cyc AND absmax 1.0 (wave-uniform f32 frame spans only ~103 nats;
// real spatial spread exceeds it -> mass flushed). Fix for BOTH: per-lane
// frames. renorm = lane-local (7 fmax + 8 ldexp, ZERO shuffles, every 4
// steps); state (a0..a7, E), true alpha = a*2^E. Boundary crosses lanes as
// (value,E) pair via 2 pipelined shuffles (latency hidden, consumed next
// step); consumer u = ldexp(up, Eup-E) -- frame-tagged, renorm-invariant.
// Adoption (D>64 && up!=0): incoming dwarfs local frame -> rebase (up!=0
// guard keeps permanently-junk lanes from adopting; empty lanes drift
// -125/renorm > max real decay 104 bits/4 steps, guaranteeing adoption when
// mass first arrives). Load skeleton = R7/R1 verbatim (NO inline asm: R5/R6
// crashed with asm+f32; R7 passed without).
__global__ __launch_bounds__(64, 1)
void k_ctc(const float* __restrict__ P,
           const int* __restrict__ targets,
           const int* __restrict__ in_len,
           const int* __restrict__ tgt_len,
           float* __restrict__ nll_out) {
  const int n = blockIdx.x;
  const int lane = threadIdx.x;
  const int Tn = in_len[n];
  const float* g = P + (size_t)n * T_ * LP_;
  const int* tg = targets + n * S_;

  // skip multipliers for odd positions j=1,3,5,7 -> label index m0+0..3
  const int m0 = lane * 4;
  auto skv = [&](int m) -> float {
    int mi = (m >= 1 && m < S_) ? m : 1;     // clamp: no OOB read
    return (m >= 1 && m < S_ && tg[mi] != tg[mi - 1]) ? 1.0f : 0.0f;
  };
  const float sk1 = skv(m0), sk3 = skv(m0 + 1);
  const float sk5 = skv(m0 + 2), sk7 = skv(m0 + 3);

  float a0 = 0.0f, a1 = 0.0f, a2 = 0.0f, a3 = 0.0f;
  float a4 = 0.0f, a5 = 0.0f, a6 = 0.0f, a7 = 0.0f;
  float up = 0.0f;   // alpha(t-1, lane*8-1) in SRC frame; shuffled 1 step ahead
  int   E = 0;       // my frame: true alpha = a * 2^E
  int   Eup = 0;     // frame of 'up'
  if (lane == 0) { a0 = g[0]; a1 = g[1]; }

  const float* gl = g + lane * 8;
  const int src = (lane + 63) & 63;

  auto step = [&](const float4& A, const float4& B) {
    int D = Eup - E;
    if (D > 64 && up != 0.0f) {
      // incoming mass dwarfs local frame: rebase. Local values shift down by
      // D (>=65) -- anything lost is <2^-64 relative to the incoming mass.
      a0 = LDX(a0, -D); a1 = LDX(a1, -D); a2 = LDX(a2, -D); a3 = LDX(a3, -D);
      a4 = LDX(a4, -D); a5 = LDX(a5, -D); a6 = LDX(a6, -D); a7 = LDX(a7, -D);
      E = Eup; D = 0;
    }
    float u = LDX(up, D);   // D<=64 -> u <= 2^65, no overflow; D very
                            // negative -> flush to 0 (mass << local precision)
    // a7n/a6n first: lane-local only -> shuffles for NEXT step issue early
    float a7n = (a7 + a6 + sk7 * a5) * B.w;
    float a6n = (a6 + a5) * B.z;
    float upn = __shfl(a7n, src);        // consumed next step
    int  Eupn = __shfl(E, src);          // coherent (value,frame) snapshot
    float a5n = (a5 + a4 + sk5 * a3) * B.y;
    float a4n = (a4 + a3) * B.x;
    float a3n = (a3 + a2 + sk3 * a1) * A.w;
    float a2n = (a2 + a1) * A.z;
    float a1n = (a1 + a0 + sk1 * u) * A.y;
    float a0n = (a0 + u) * A.x;          // even: no skip ever
    if (lane == 0) upn = 0.0f;           // no predecessor
    a0 = a0n; a1 = a1n; a2 = a2n; a3 = a3n;
    a4 = a4n; a5 = a5n; a6 = a6n; a7 = a7n;
    up = upn; Eup = Eupn;
  };

  // lane-LOCAL renorm (no shuffles): scale lane max into [2^-2, 2^-1).
  // m==0 (empty lane): biased exp 0 -> R=125 -> E drifts down faster than
  // any real decay (<=104 bits/4 steps), guaranteeing adoption on arrival.
  // up/Eup untouched: frame-tagged, D compensates.
  auto renorm = [&]() {
    float m = fmaxf(fmaxf(fmaxf(a0, a1), fmaxf(a2, a3)),
                    fmaxf(fmaxf(a4, a5), fmaxf(a6, a7)));
    int R = 125 - ((__float_as_int(m) >> 23) & 0xFF);
    a0 = LDX(a0, R); a1 = LDX(a1, R); a2 = LDX(a2, R); a3 = LDX(a3, R);
    a4 = LDX(a4, R); a5 = LDX(a5, R); a6 = LDX(a6, R); a7 = LDX(a7, R);
    E -= R;
  };

  // load rows for one step into a float4 pair (clamped: rows up to T_-1
  // always exist in P; clamped rows are prefetch garbage, never consumed)
  auto ld = [&](int tt, float4& A, float4& B) {
    if (tt > T_ - 1) tt = T_ - 1;
    const float* p = gl + (size_t)tt * LP_;
    A = *reinterpret_cast<const float4*>(p);
    B = *reinterpret_cast<const float4*>(p + 4);
  };

  float4 A0[DPF], B0[DPF], A1[DPF], B1[DPF];
#pragma unroll
  for (int d = 0; d < DPF; ++d) ld(1 + d, A0[d], B0[d]);

  // invariant at each phase top: A0/B0 (resp. A1/B1) hold rows t..t+DPF-1
  int t = 1;
  int rem = Tn - 1;               // total steps to execute (t = 1..Tn-1)
  while (rem >= 2 * DPF) {
    // phase 1: prefetch next block into A1/B1, compute from A0/B0
#pragma unroll
    for (int d = 0; d < DPF; ++d) ld(t + DPF + d, A1[d], B1[d]);
#pragma unroll
    for (int d = 0; d < DPF; ++d) {
      step(A0[d], B0[d]);
      if ((d & 3) == 3) renorm();   // every 4 steps (f32 range budget)
    }
    t += DPF;
    // phase 2: prefetch next block into A0/B0, compute from A1/B1
#pragma unroll
    for (int d = 0; d < DPF; ++d) ld(t + DPF + d, A0[d], B0[d]);
#pragma unroll
    for (int d = 0; d < DPF; ++d) {
      step(A1[d], B1[d]);
      if ((d & 3) == 3) renorm();
    }
    t += DPF;
    rem -= 2 * DPF;
  }
  // rem in [0, 2*DPF-1]; A0/B0 hold rows t..t+DPF-1
  if (rem >= DPF) {
#pragma unroll
    for (int d = 0; d < DPF; ++d) ld(t + DPF + d, A1[d], B1[d]);
#pragma unroll
    for (int d = 0; d < DPF; ++d) {
      step(A0[d], B0[d]);
      if ((d & 3) == 3) renorm();
    }
    t += DPF; rem -= DPF;
#pragma unroll
    for (int d = 0; d < DPF; ++d) {
      if (d < rem) step(A1[d], B1[d]);
      if ((d & 3) == 3) renorm();   // exact scaling: harmless past the end
    }
  } else {
#pragma unroll
    for (int d = 0; d < DPF; ++d) {
      if (d < rem) step(A0[d], B0[d]);
      if ((d & 3) == 3) renorm();
    }
  }

  __shared__ float sa[LP_];
  __shared__ int   se[LP_];
  sa[lane * 8 + 0] = a0; sa[lane * 8 + 1] = a1;
  sa[lane * 8 + 2] = a2; sa[lane * 8 + 3] = a3;
  sa[lane * 8 + 4] = a4; sa[lane * 8 + 5] = a5;
  sa[lane * 8 + 6] = a6; sa[lane * 8 + 7] = a7;
#pragma unroll
  for (int j = 0; j < 8; ++j) se[lane * 8 + j] = E;
  __syncthreads();
  if (lane == 0) {
    int tl = tgt_len[n];
    float v1 = sa[2 * tl - 1], v2 = sa[2 * tl];
    int   E1 = se[2 * tl - 1], E2 = se[2 * tl];
    int   Em = max(E1, E2);
    double v = ldexp((double)v1, E1 - Em) + ldexp((double)v2, E2 - Em);
    int ee;
    double mfr = frexp(v, &ee);
    nll_out[n] = -LN2_ * ((float)(Em + ee) + log2f((float)mfr));
  }
}

__global__ void k_final(const float* __restrict__ nll,
                        const int* __restrict__ tgt_len,
                        float* __restrict__ out) {
  int lane = threadIdx.x;
  float v = 0.0f;
  if (lane < N_) v = nll[lane] / (float)tgt_len[lane];
#pragma unroll
  for (int i = 1; i < 64; i <<= 1) v += __shfl_xor(v, i);
  if (lane == 0) out[0] = v * (1.0f / N_);
}

__global__ void k_sentinel(float* out) { out[0] = -12345.0f; }

extern "C" void kernel_launch(void* const* d_in, const int* in_sizes, int n_in,
                              void* d_out, int out_size, void* d_ws, size_t ws_size,
                              hipStream_t stream) {
  const float* logits = (const float*)d_in[0];
  const int* targets  = (const int*)d_in[1];
  const int* in_len   = (const int*)d_in[2];
  const int* tgt_len  = (const int*)d_in[3];
  float* out = (float*)d_out;

  size_t gbytes = (size_t)N_ * T_ * LP_ * sizeof(float);  // ~104.9 MB
  if (ws_size < gbytes + 256) {
    k_sentinel<<<1, 1, 0, stream>>>(out);
    return;
  }
  float* G = (float*)d_ws;
  float* nll = (float*)((char*)d_ws + gbytes);

  k_softmax_gather<<<(N_ * T_) / 4, 256, 0, stream>>>(logits, targets, tgt_len, G);
  k_ctc<<<N_, 64, 0, stream>>>(G, targets, in_len, tgt_len, nll);
  k_final<<<1, 64, 0, stream>>>(nll, tgt_len, out);
}

// Round 9
// 477.345 us; speedup vs baseline: 1.0962x; 1.0618x over previous
//
#include <hip/hip_runtime.h>
#include <hip/hip_bf16.h>

#define N_    32
#define T_    1600
#define C_    1024
#define S_    200
#define L_    401       // 2*S+1
#define LP_   512       // padded
#define BLANK_ 4
#define LN2_  0.69314718055994531f
#define L2E_  1.44269504088896341f
#define DPF   8

#if __has_builtin(__builtin_amdgcn_exp2f)
#define EXP2(x) __builtin_amdgcn_exp2f(x)
#else
#define EXP2(x) exp2f(x)
#endif
#if __has_builtin(__builtin_amdgcn_rcpf)
#define RCP(x) __builtin_amdgcn_rcpf(x)
#else
#define RCP(x) (1.0f / (x))
#endif
#if __has_builtin(__builtin_amdgcn_ldexpf)
#define LDX(x, e) __builtin_amdgcn_ldexpf((x), (e))
#else
#define LDX(x, e) ldexpf((x), (e))
#endif

// Kernel 1: one wave per (n,t) row. Wave-shuffle softmax, row staged in LDS,
// gather ext-label classes, write LINEAR probabilities P[n][t][l].
// Junk positions (l > 2*tgt_len[n], never read) are zeroed so their alphas
// stay exactly 0 and never pollute anything downstream.
__global__ __launch_bounds__(256)
void k_softmax_gather(const float* __restrict__ logits,
                      const int* __restrict__ targets,
                      const int* __restrict__ tgt_len,
                      float* __restrict__ P) {
  const int row  = blockIdx.x * 4 + (threadIdx.x >> 6);  // n*T_ + t
  const int lane = threadIdx.x & 63;
  const int wv   = threadIdx.x >> 6;
  const int n    = row / T_;
  const float* x = logits + (size_t)row * C_;
  __shared__ float sh[4][C_];

  float4 v[4];
#pragma unroll
  for (int i = 0; i < 4; ++i)
    v[i] = reinterpret_cast<const float4*>(x)[i * 64 + lane];

  float mx = v[0].x;
#pragma unroll
  for (int i = 0; i < 4; ++i)
    mx = fmaxf(mx, fmaxf(fmaxf(v[i].x, v[i].y), fmaxf(v[i].z, v[i].w)));
#pragma unroll
  for (int i = 1; i < 64; i <<= 1) mx = fmaxf(mx, __shfl_xor(mx, i));

  float s = 0.0f;
#pragma unroll
  for (int i = 0; i < 4; ++i) {
    s += EXP2((v[i].x - mx) * L2E_) + EXP2((v[i].y - mx) * L2E_)
       + EXP2((v[i].z - mx) * L2E_) + EXP2((v[i].w - mx) * L2E_);
  }
#pragma unroll
  for (int i = 1; i < 64; i <<= 1) s += __shfl_xor(s, i);
  float rz = RCP(s);

#pragma unroll
  for (int i = 0; i < 4; ++i)
    reinterpret_cast<float4*>(sh[wv])[i * 64 + lane] = v[i];
  __syncthreads();

  const int* tg = targets + n * S_;
  const int lmax = 2 * tgt_len[n];   // live region: l in [0, 2*tl]
  float* out = P + (size_t)row * LP_;
#pragma unroll
  for (int i = 0; i < 8; ++i) {
    int l = lane + i * 64;
    float p = 0.0f;
    if (l <= lmax) {
      int c = (l & 1) ? tg[(l - 1) >> 1] : BLANK_;
      p = EXP2((sh[wv][c] - mx) * L2E_) * rz;
    }
    out[l] = p;
  }
}

// DPP wave_shr:1 (dpp_ctrl 0x138): lane i reads lane i-1, lane 0 reads 0
// (bound_ctrl=1). VALU-pipe cross-lane -- no LDS, no lgkmcnt, ~4-8 cyc.
__device__ __forceinline__ float dpp_shr1_f(float x) {
  return __int_as_float(__builtin_amdgcn_update_dpp(
      0, __float_as_int(x), 0x138, 0xF, 0xF, true));
}
__device__ __forceinline__ int dpp_shr1_i(int x) {
  return __builtin_amdgcn_update_dpp(0, x, 0x138, 0xF, 0xF, true);
}

// Kernel 2: CTC forward, ONE wave per sequence, lane owns 8 contiguous
// positions, f32 with PER-LANE exponent frames (R8: absmax 0.0 -- exact).
//
// Cycle model fitted across R0/R1/R4/R7/R8: every structure paid ~100-120
// cyc/step for __shfl (ds_bpermute LDS latency, fully exposed at 1 wave/SIMD;
// the compiler's lgkmcnt(0) lands with only ~60 cyc of issuable work after
// the bpermute). R8 paid it twice (up + Eup) -> 320 cyc/step. THIS ROUND:
// the cross-lane traffic is a shift-by-one-lane, which DPP does in the VALU
// pipe: wave_shr:1, bound_ctrl=1 zero-fills lane 0 (also deletes the lane==0
// cndmask; lane 0's Eup=0 is harmless since up=0 and adoption requires
// up!=0). Everything else is R8 verbatim: lane-local renorm every 4 steps
// (7 fmax + 8 ldexp, zero cross-lane), frame-tagged (up,Eup) boundary pair,
// adoption rebase on D>64 && up!=0, R7/R1 compiler-scheduled load skeleton
// (NO inline asm).
__global__ __launch_bounds__(64, 1)
void k_ctc(const float* __restrict__ P,
           const int* __restrict__ targets,
           const int* __restrict__ in_len,
           const int* __restrict__ tgt_len,
           float* __restrict__ nll_out) {
  const int n = blockIdx.x;
  const int lane = threadIdx.x;
  const int Tn = in_len[n];
  const float* g = P + (size_t)n * T_ * LP_;
  const int* tg = targets + n * S_;

  // skip multipliers for odd positions j=1,3,5,7 -> label index m0+0..3
  const int m0 = lane * 4;
  auto skv = [&](int m) -> float {
    int mi = (m >= 1 && m < S_) ? m : 1;     // clamp: no OOB read
    return (m >= 1 && m < S_ && tg[mi] != tg[mi - 1]) ? 1.0f : 0.0f;
  };
  const float sk1 = skv(m0), sk3 = skv(m0 + 1);
  const float sk5 = skv(m0 + 2), sk7 = skv(m0 + 3);

  float a0 = 0.0f, a1 = 0.0f, a2 = 0.0f, a3 = 0.0f;
  float a4 = 0.0f, a5 = 0.0f, a6 = 0.0f, a7 = 0.0f;
  float up = 0.0f;   // alpha(t-1, lane*8-1) in SRC frame; DPP'd 1 step ahead
  int   E = 0;       // my frame: true alpha = a * 2^E
  int   Eup = 0;     // frame of 'up'
  if (lane == 0) { a0 = g[0]; a1 = g[1]; }

  const float* gl = g + lane * 8;

  auto step = [&](const float4& A, const float4& B) {
    int D = Eup - E;
    if (D > 64 && up != 0.0f) {
      // incoming mass dwarfs local frame: rebase. Local values shift down by
      // D (>=65) -- anything lost is <2^-64 relative to the incoming mass.
      a0 = LDX(a0, -D); a1 = LDX(a1, -D); a2 = LDX(a2, -D); a3 = LDX(a3, -D);
      a4 = LDX(a4, -D); a5 = LDX(a5, -D); a6 = LDX(a6, -D); a7 = LDX(a7, -D);
      E = Eup; D = 0;
    }
    float u = LDX(up, D);   // D<=64 -> u <= 2^65, no overflow; D very
                            // negative -> flush to 0 (mass << local precision)
    // a7n first: its DPP for NEXT step issues right after (VALU, no wait)
    float a7n = (a7 + a6 + sk7 * a5) * B.w;
    float a6n = (a6 + a5) * B.z;
    float upn = dpp_shr1_f(a7n);         // lane0 -> 0 via bound_ctrl
    int  Eupn = dpp_shr1_i(E);           // coherent (value,frame) snapshot
    float a5n = (a5 + a4 + sk5 * a3) * B.y;
    float a4n = (a4 + a3) * B.x;
    float a3n = (a3 + a2 + sk3 * a1) * A.w;
    float a2n = (a2 + a1) * A.z;
    float a1n = (a1 + a0 + sk1 * u) * A.y;
    float a0n = (a0 + u) * A.x;          // even: no skip ever
    a0 = a0n; a1 = a1n; a2 = a2n; a3 = a3n;
    a4 = a4n; a5 = a5n; a6 = a6n; a7 = a7n;
    up = upn; Eup = Eupn;
  };

  // lane-LOCAL renorm (no cross-lane): scale lane max into [2^-2, 2^-1).
  // m==0 (empty lane): biased exp 0 -> R=125 -> E drifts down faster than
  // any real decay (<=104 bits/4 steps), guaranteeing adoption on arrival.
  // up/Eup untouched: frame-tagged, D compensates.
  auto renorm = [&]() {
    float m = fmaxf(fmaxf(fmaxf(a0, a1), fmaxf(a2, a3)),
                    fmaxf(fmaxf(a4, a5), fmaxf(a6, a7)));
    int R = 125 - ((__float_as_int(m) >> 23) & 0xFF);
    a0 = LDX(a0, R); a1 = LDX(a1, R); a2 = LDX(a2, R); a3 = LDX(a3, R);
    a4 = LDX(a4, R); a5 = LDX(a5, R); a6 = LDX(a6, R); a7 = LDX(a7, R);
    E -= R;
  };

  // load rows for one step into a float4 pair (clamped: rows up to T_-1
  // always exist in P; clamped rows are prefetch garbage, never consumed)
  auto ld = [&](int tt, float4& A, float4& B) {
    if (tt > T_ - 1) tt = T_ - 1;
    const float* p = gl + (size_t)tt * LP_;
    A = *reinterpret_cast<const float4*>(p);
    B = *reinterpret_cast<const float4*>(p + 4);
  };

  float4 A0[DPF], B0[DPF], A1[DPF], B1[DPF];
#pragma unroll
  for (int d = 0; d < DPF; ++d) ld(1 + d, A0[d], B0[d]);

  // invariant at each phase top: A0/B0 (resp. A1/B1) hold rows t..t+DPF-1
  int t = 1;
  int rem = Tn - 1;               // total steps to execute (t = 1..Tn-1)
  while (rem >= 2 * DPF) {
    // phase 1: prefetch next block into A1/B1, compute from A0/B0
#pragma unroll
    for (int d = 0; d < DPF; ++d) ld(t + DPF + d, A1[d], B1[d]);
#pragma unroll
    for (int d = 0; d < DPF; ++d) {
      step(A0[d], B0[d]);
      if ((d & 3) == 3) renorm();   // every 4 steps (f32 range budget)
    }
    t += DPF;
    // phase 2: prefetch next block into A0/B0, compute from A1/B1
#pragma unroll
    for (int d = 0; d < DPF; ++d) ld(t + DPF + d, A0[d], B0[d]);
#pragma unroll
    for (int d = 0; d < DPF; ++d) {
      step(A1[d], B1[d]);
      if ((d & 3) == 3) renorm();
    }
    t += DPF;
    rem -= 2 * DPF;
  }
  // rem in [0, 2*DPF-1]; A0/B0 hold rows t..t+DPF-1
  if (rem >= DPF) {
#pragma unroll
    for (int d = 0; d < DPF; ++d) ld(t + DPF + d, A1[d], B1[d]);
#pragma unroll
    for (int d = 0; d < DPF; ++d) {
      step(A0[d], B0[d]);
      if ((d & 3) == 3) renorm();
    }
    t += DPF; rem -= DPF;
#pragma unroll
    for (int d = 0; d < DPF; ++d) {
      if (d < rem) step(A1[d], B1[d]);
      if ((d & 3) == 3) renorm();   // exact scaling: harmless past the end
    }
  } else {
#pragma unroll
    for (int d = 0; d < DPF; ++d) {
      if (d < rem) step(A0[d], B0[d]);
      if ((d & 3) == 3) renorm();
    }
  }

  __shared__ float sa[LP_];
  __shared__ int   se[LP_];
  sa[lane * 8 + 0] = a0; sa[lane * 8 + 1] = a1;
  sa[lane * 8 + 2] = a2; sa[lane * 8 + 3] = a3;
  sa[lane * 8 + 4] = a4; sa[lane * 8 + 5] = a5;
  sa[lane * 8 + 6] = a6; sa[lane * 8 + 7] = a7;
#pragma unroll
  for (int j = 0; j < 8; ++j) se[lane * 8 + j] = E;
  __syncthreads();
  if (lane == 0) {
    int tl = tgt_len[n];
    float v1 = sa[2 * tl - 1], v2 = sa[2 * tl];
    int   E1 = se[2 * tl - 1], E2 = se[2 * tl];
    int   Em = max(E1, E2);
    double v = ldexp((double)v1, E1 - Em) + ldexp((double)v2, E2 - Em);
    int ee;
    double mfr = frexp(v, &ee);
    nll_out[n] = -LN2_ * ((float)(Em + ee) + log2f((float)mfr));
  }
}

__global__ void k_final(const float* __restrict__ nll,
                        const int* __restrict__ tgt_len,
                        float* __restrict__ out) {
  int lane = threadIdx.x;
  float v = 0.0f;
  if (lane < N_) v = nll[lane] / (float)tgt_len[lane];
#pragma unroll
  for (int i = 1; i < 64; i <<= 1) v += __shfl_xor(v, i);
  if (lane == 0) out[0] = v * (1.0f / N_);
}

__global__ void k_sentinel(float* out) { out[0] = -12345.0f; }

extern "C" void kernel_launch(void* const* d_in, const int* in_sizes, int n_in,
                              void* d_out, int out_size, void* d_ws, size_t ws_size,
                              hipStream_t stream) {
  const float* logits = (const float*)d_in[0];
  const int* targets  = (const int*)d_in[1];
  const int* in_len   = (const int*)d_in[2];
  const int* tgt_len  = (const int*)d_in[3];
  float* out = (float*)d_out;

  size_t gbytes = (size_t)N_ * T_ * LP_ * sizeof(float);  // ~104.9 MB
  if (ws_size < gbytes + 256) {
    k_sentinel<<<1, 1, 0, stream>>>(out);
    return;
  }
  float* G = (float*)d_ws;
  float* nll = (float*)((char*)d_ws + gbytes);

  k_softmax_gather<<<(N_ * T_) / 4, 256, 0, stream>>>(logits, targets, tgt_len, G);
  k_ctc<<<N_, 64, 0, stream>>>(G, targets, in_len, tgt_len, nll);
  k_final<<<1, 64, 0, stream>>>(nll, tgt_len, out);
}